// Round 1
// baseline (515.857 us; speedup 1.0000x reference)
//
#include <hip/hip_runtime.h>

#define N_NODES 50000
#define N_EDGES 800000
// IN_F = HID_F = 128, OUT_F = 64

// ---------------- workspace layout (bytes) ----------------
// bufA       : 0          .. 25,600,000   (50000*128 f32)
// bufB       : 25,600,000 .. 51,200,000
// row_start  : 51,200,000 (+200,004)
// inv_deg    : 51,400,192 (+200,000)
// cnt        : 51,600,192 (+200,000)
// cursor     : 51,800,192 (+200,000)
// csr_src    : 52,000,192 (+3,200,000)
// Wt pool    : 55,200,192 (+360,448)   total ~55.6 MB
#define OFF_BUFA      0UL
#define OFF_BUFB      25600000UL
#define OFF_ROWSTART  51200000UL
#define OFF_INVDEG    51400192UL
#define OFF_CNT       51600192UL
#define OFF_CURSOR    51800192UL
#define OFF_CSR       52000192UL
#define OFF_WT        55200192UL

// ---------------- CSR build ----------------
__global__ __launch_bounds__(256)
void hist_kernel(const int* __restrict__ dst, int* __restrict__ cnt, int E) {
  int i = blockIdx.x * 256 + threadIdx.x;
  if (i < E) atomicAdd(&cnt[dst[i]], 1);
}

__global__ __launch_bounds__(1024)
void scan_kernel(const int* __restrict__ cnt, int* __restrict__ row_start,
                 float* __restrict__ inv_deg, int n) {
  __shared__ int wsum[16];
  const int tid = threadIdx.x;
  const int lane = tid & 63;
  const int wid = tid >> 6;
  int base = 0;
  for (int start = 0; start < n; start += 4096) {
    int i0 = start + tid * 4;
    int v0 = (i0 + 0 < n) ? cnt[i0 + 0] : 0;
    int v1 = (i0 + 1 < n) ? cnt[i0 + 1] : 0;
    int v2 = (i0 + 2 < n) ? cnt[i0 + 2] : 0;
    int v3 = (i0 + 3 < n) ? cnt[i0 + 3] : 0;
    int p1 = v0, p2 = v0 + v1, p3 = v0 + v1 + v2;
    int tot = p3 + v3;
    int x = tot;
    #pragma unroll
    for (int off = 1; off < 64; off <<= 1) {
      int y = __shfl_up(x, off);
      if (lane >= off) x += y;
    }
    if (lane == 63) wsum[wid] = x;
    __syncthreads();
    if (tid < 16) {
      int w = wsum[tid];
      #pragma unroll
      for (int off = 1; off < 16; off <<= 1) {
        int y = __shfl_up(w, off);
        if (tid >= off) w += y;
      }
      wsum[tid] = w;  // inclusive over waves
    }
    __syncthreads();
    int wexcl = (wid == 0) ? 0 : wsum[wid - 1];
    int texcl = base + wexcl + (x - tot);
    if (i0 + 0 < n) { row_start[i0 + 0] = texcl;      inv_deg[i0 + 0] = 1.0f / fmaxf((float)v0, 1.0f); }
    if (i0 + 1 < n) { row_start[i0 + 1] = texcl + p1; inv_deg[i0 + 1] = 1.0f / fmaxf((float)v1, 1.0f); }
    if (i0 + 2 < n) { row_start[i0 + 2] = texcl + p2; inv_deg[i0 + 2] = 1.0f / fmaxf((float)v2, 1.0f); }
    if (i0 + 3 < n) { row_start[i0 + 3] = texcl + p3; inv_deg[i0 + 3] = 1.0f / fmaxf((float)v3, 1.0f); }
    int ctot = wsum[15];
    __syncthreads();
    base += ctot;
  }
  if (tid == 0) row_start[n] = base;
}

__global__ __launch_bounds__(256)
void scatter_kernel(const int* __restrict__ src, const int* __restrict__ dst,
                    const int* __restrict__ row_start, int* __restrict__ cursor,
                    int* __restrict__ csr_src, int E) {
  int i = blockIdx.x * 256 + threadIdx.x;
  if (i < E) {
    int d = dst[i];
    int pos = atomicAdd(&cursor[d], 1);
    csr_src[row_start[d] + pos] = src[i];
  }
}

// ---------------- W pre-transpose:  W[nout][128] -> Wt[128][nout] ----------------
__global__ __launch_bounds__(256)
void transpose_w(const float* __restrict__ W, float* __restrict__ Wt, int nout) {
  int i = blockIdx.x * 256 + threadIdx.x;
  int total = nout * 128;
  if (i < total) {
    int k = i / nout;
    int c = i - k * nout;
    Wt[i] = W[c * 128 + k];
  }
}

// ---------------- aggregation: out[v] = x[v] + (1/max(deg,1)) * sum_{(s->v)} x[s] ----------------
__global__ __launch_bounds__(256)
void agg_kernel(const float* __restrict__ x, const int* __restrict__ csr_src,
                const int* __restrict__ row_start, const float* __restrict__ inv_deg,
                float* __restrict__ out) {
  int node = blockIdx.x * 4 + (threadIdx.x >> 6);
  int lane = threadIdx.x & 63;
  if (node >= N_NODES) return;
  int beg = row_start[node];
  int end = row_start[node + 1];
  float a0 = 0.f, a1 = 0.f, b0 = 0.f, b1 = 0.f;
  int e = beg;
  for (; e + 1 < end; e += 2) {
    int s0 = csr_src[e];
    int s1 = csr_src[e + 1];
    float2 u = *reinterpret_cast<const float2*>(x + (size_t)s0 * 128 + lane * 2);
    float2 v = *reinterpret_cast<const float2*>(x + (size_t)s1 * 128 + lane * 2);
    a0 += u.x; a1 += u.y; b0 += v.x; b1 += v.y;
  }
  if (e < end) {
    int s0 = csr_src[e];
    float2 u = *reinterpret_cast<const float2*>(x + (size_t)s0 * 128 + lane * 2);
    a0 += u.x; a1 += u.y;
  }
  float inv = inv_deg[node];
  float2 xv = *reinterpret_cast<const float2*>(x + (size_t)node * 128 + lane * 2);
  float2 o = make_float2(xv.x + (a0 + b0) * inv, xv.y + (a1 + b1) * inv);
  *reinterpret_cast<float2*>(out + (size_t)node * 128 + lane * 2) = o;
}

// ---------------- GEMM: Y[M][NOUT] = relu?(X[M][128] @ Wt(k-major)[128][NOUT] + bias) ----------------
// Xt LDS layout: [k][row] (transposed), granule-XOR swizzle to break transpose-write bank conflicts.
__device__ __forceinline__ int swz_idx(int k, int col) {
  int g = (col >> 2) ^ (((k >> 2) & 7) << 1);
  return k * 128 + (g << 2) + (col & 3);
}

template <int TN, bool RELU>
__global__ __launch_bounds__(256)
void gemm_bias(const float* __restrict__ X, const float* __restrict__ Wt,
               const float* __restrict__ bias, float* __restrict__ Y, int M) {
  constexpr int NOUT = TN * 16;
  __shared__ float Xt[128 * 128];  // 64 KB
  const int tid = threadIdx.x;
  const int m0 = blockIdx.x * 128;

  // stage + transpose X tile: 128 rows x 128 k
  for (int f = tid; f < 128 * 32; f += 256) {
    int row = f >> 5;
    int k4 = (f & 31) << 2;
    float4 v = make_float4(0.f, 0.f, 0.f, 0.f);
    if (m0 + row < M)
      v = *reinterpret_cast<const float4*>(X + (size_t)(m0 + row) * 128 + k4);
    Xt[swz_idx(k4 + 0, row)] = v.x;
    Xt[swz_idx(k4 + 1, row)] = v.y;
    Xt[swz_idx(k4 + 2, row)] = v.z;
    Xt[swz_idx(k4 + 3, row)] = v.w;
  }
  __syncthreads();

  const int rg = tid >> 4;  // 16 row groups * 8 rows
  const int cg = tid & 15;  // 16 col groups * TN cols
  float acc[8][TN];
  #pragma unroll
  for (int r = 0; r < 8; ++r)
    #pragma unroll
    for (int j = 0; j < TN; ++j) acc[r][j] = 0.f;

  #pragma unroll 2
  for (int k = 0; k < 128; ++k) {
    float a[8];
    *reinterpret_cast<float4*>(&a[0]) = *reinterpret_cast<const float4*>(&Xt[swz_idx(k, rg * 8)]);
    *reinterpret_cast<float4*>(&a[4]) = *reinterpret_cast<const float4*>(&Xt[swz_idx(k, rg * 8 + 4)]);
    float b[TN];
    #pragma unroll
    for (int j = 0; j < TN; j += 4)
      *reinterpret_cast<float4*>(&b[j]) =
          *reinterpret_cast<const float4*>(Wt + k * NOUT + cg * TN + j);
    #pragma unroll
    for (int r = 0; r < 8; ++r)
      #pragma unroll
      for (int j = 0; j < TN; ++j) acc[r][j] = fmaf(a[r], b[j], acc[r][j]);
  }

  float bv[TN];
  #pragma unroll
  for (int j = 0; j < TN; ++j) bv[j] = bias[cg * TN + j];

  #pragma unroll
  for (int r = 0; r < 8; ++r) {
    int row = m0 + rg * 8 + r;
    if (row < M) {
      #pragma unroll
      for (int j = 0; j < TN; j += 4) {
        float4 o;
        o.x = acc[r][j + 0] + bv[j + 0];
        o.y = acc[r][j + 1] + bv[j + 1];
        o.z = acc[r][j + 2] + bv[j + 2];
        o.w = acc[r][j + 3] + bv[j + 3];
        if (RELU) {
          o.x = fmaxf(o.x, 0.f); o.y = fmaxf(o.y, 0.f);
          o.z = fmaxf(o.z, 0.f); o.w = fmaxf(o.w, 0.f);
        }
        *reinterpret_cast<float4*>(Y + (size_t)row * NOUT + cg * TN + j) = o;
      }
    }
  }
}

// ---------------- launch ----------------
extern "C" void kernel_launch(void* const* d_in, const int* in_sizes, int n_in,
                              void* d_out, int out_size, void* d_ws, size_t ws_size,
                              hipStream_t stream) {
  const float* feat = (const float*)d_in[0];
  const int*   src  = (const int*)d_in[1];
  const int*   dst  = (const int*)d_in[2];
  const float* W1a = (const float*)d_in[3];  const float* b1a = (const float*)d_in[4];
  const float* W1b = (const float*)d_in[5];  const float* b1b = (const float*)d_in[6];
  const float* W2a = (const float*)d_in[7];  const float* b2a = (const float*)d_in[8];
  const float* W2b = (const float*)d_in[9];  const float* b2b = (const float*)d_in[10];
  const float* W3a = (const float*)d_in[11]; const float* b3a = (const float*)d_in[12];
  const float* W3b = (const float*)d_in[13]; const float* b3b = (const float*)d_in[14];

  char* ws = (char*)d_ws;
  float* bufA      = (float*)(ws + OFF_BUFA);
  float* bufB      = (float*)(ws + OFF_BUFB);
  int*   row_start = (int*)  (ws + OFF_ROWSTART);
  float* inv_deg   = (float*)(ws + OFF_INVDEG);
  int*   cnt       = (int*)  (ws + OFF_CNT);
  int*   cursor    = (int*)  (ws + OFF_CURSOR);
  int*   csr       = (int*)  (ws + OFF_CSR);
  float* wt        = (float*)(ws + OFF_WT);
  float* Wt1a = wt;            float* Wt1b = wt + 16384;
  float* Wt2a = wt + 32768;    float* Wt2b = wt + 49152;
  float* Wt3a = wt + 65536;    float* Wt3b = wt + 81920;  // 128x64

  hipMemsetAsync(cnt, 0, N_NODES * sizeof(int), stream);
  hipMemsetAsync(cursor, 0, N_NODES * sizeof(int), stream);

  hist_kernel<<<(N_EDGES + 255) / 256, 256, 0, stream>>>(dst, cnt, N_EDGES);
  scan_kernel<<<1, 1024, 0, stream>>>(cnt, row_start, inv_deg, N_NODES);
  scatter_kernel<<<(N_EDGES + 255) / 256, 256, 0, stream>>>(src, dst, row_start, cursor, csr, N_EDGES);

  transpose_w<<<64, 256, 0, stream>>>(W1a, Wt1a, 128);
  transpose_w<<<64, 256, 0, stream>>>(W1b, Wt1b, 128);
  transpose_w<<<64, 256, 0, stream>>>(W2a, Wt2a, 128);
  transpose_w<<<64, 256, 0, stream>>>(W2b, Wt2b, 128);
  transpose_w<<<64, 256, 0, stream>>>(W3a, Wt3a, 128);
  transpose_w<<<32, 256, 0, stream>>>(W3b, Wt3b, 64);

  const int GB = (N_NODES + 127) / 128;  // 391 blocks

  // layer 1
  agg_kernel<<<(N_NODES + 3) / 4, 256, 0, stream>>>(feat, csr, row_start, inv_deg, bufA);
  gemm_bias<8, true><<<GB, 256, 0, stream>>>(bufA, Wt1a, b1a, bufB, N_NODES);
  gemm_bias<8, true><<<GB, 256, 0, stream>>>(bufB, Wt1b, b1b, bufA, N_NODES);
  // layer 2
  agg_kernel<<<(N_NODES + 3) / 4, 256, 0, stream>>>(bufA, csr, row_start, inv_deg, bufB);
  gemm_bias<8, true><<<GB, 256, 0, stream>>>(bufB, Wt2a, b2a, bufA, N_NODES);
  gemm_bias<8, true><<<GB, 256, 0, stream>>>(bufA, Wt2b, b2b, bufB, N_NODES);
  // head
  gemm_bias<8, true><<<GB, 256, 0, stream>>>(bufB, Wt3a, b3a, bufA, N_NODES);
  gemm_bias<4, false><<<GB, 256, 0, stream>>>(bufA, Wt3b, b3b, (float*)d_out, N_NODES);
}

// Round 3
// 302.223 us; speedup vs baseline: 1.7069x; 1.7069x over previous
//
#include <hip/hip_runtime.h>

#define N_NODES 50000
#define N_EDGES 800000

typedef __attribute__((ext_vector_type(8))) short bf16x8;
typedef __attribute__((ext_vector_type(4))) float f32x4;

// ---------------- workspace layout (bytes) ----------------
#define OFF_BUFA      0UL
#define OFF_BUFB      25600000UL
#define OFF_ROWSTART  51200000UL   // 200,000
#define OFF_CNT       51400000UL   // 200,000
#define OFF_CURSOR    51600000UL   // 200,000
#define OFF_CTR       51800000UL   // 256
#define OFF_CSR       51800256UL   // 3,200,000
#define OFF_W         55000256UL   // 360,448 (bf16 hi/lo weight pool)
#define OFF_INVDEG    55400256UL   // 200,000

__device__ __forceinline__ unsigned short bf16_rne(float f) {
  unsigned u = __float_as_uint(f);
  unsigned r = (u + 0x7FFFu + ((u >> 16) & 1u)) >> 16;
  return (unsigned short)r;
}

// ---------------- CSR build ----------------
__global__ __launch_bounds__(256)
void hist_kernel(const int* __restrict__ dst, int* __restrict__ cnt, int E) {
  int i = blockIdx.x * 256 + threadIdx.x;
  if (i < E) atomicAdd(&cnt[dst[i]], 1);
}

// block-local scan + atomic base claim (row bases need not be globally ordered)
__global__ __launch_bounds__(256)
void blockscan_kernel(const int* __restrict__ cnt, int* __restrict__ row_start,
                      float* __restrict__ inv_deg, int* __restrict__ counter, int n) {
  __shared__ int wsum[4];
  __shared__ int sbase;
  int i = blockIdx.x * 256 + threadIdx.x;
  int lane = threadIdx.x & 63;
  int wid = threadIdx.x >> 6;
  int v = (i < n) ? cnt[i] : 0;
  int x = v;
  #pragma unroll
  for (int off = 1; off < 64; off <<= 1) {
    int y = __shfl_up(x, off);
    if (lane >= off) x += y;
  }
  if (lane == 63) wsum[wid] = x;
  __syncthreads();
  if (threadIdx.x == 0) {
    int t0 = wsum[0], t1 = wsum[1], t2 = wsum[2], t3 = wsum[3];
    sbase = atomicAdd(counter, t0 + t1 + t2 + t3);
    wsum[0] = 0; wsum[1] = t0; wsum[2] = t0 + t1; wsum[3] = t0 + t1 + t2;
  }
  __syncthreads();
  if (i < n) {
    row_start[i] = sbase + wsum[wid] + (x - v);
    inv_deg[i] = 1.0f / fmaxf((float)v, 1.0f);
  }
}

__global__ __launch_bounds__(256)
void scatter_kernel(const int* __restrict__ src, const int* __restrict__ dst,
                    const int* __restrict__ row_start, int* __restrict__ cursor,
                    int* __restrict__ csr_src, int E) {
  int i = blockIdx.x * 256 + threadIdx.x;
  if (i < E) {
    int d = dst[i];
    int pos = atomicAdd(&cursor[d], 1);
    csr_src[row_start[d] + pos] = src[i];
  }
}

// ---------------- weights -> bf16 hi/lo, [n][k] row-major (no transpose needed) ----------------
__global__ __launch_bounds__(256)
void wconvert(const float* __restrict__ W1a, const float* __restrict__ W1b,
              const float* __restrict__ W2a, const float* __restrict__ W2b,
              const float* __restrict__ W3a, const float* __restrict__ W3b,
              unsigned short* __restrict__ pool) {
  int i = blockIdx.x * 256 + threadIdx.x;
  const float* src;
  int base, local, msize;
  if (i < 16384)      { src = W1a; base = 0;      local = i;          msize = 16384; }
  else if (i < 32768) { src = W1b; base = 32768;  local = i - 16384;  msize = 16384; }
  else if (i < 49152) { src = W2a; base = 65536;  local = i - 32768;  msize = 16384; }
  else if (i < 65536) { src = W2b; base = 98304;  local = i - 49152;  msize = 16384; }
  else if (i < 81920) { src = W3a; base = 131072; local = i - 65536;  msize = 16384; }
  else if (i < 90112) { src = W3b; base = 163840; local = i - 81920;  msize = 8192;  }
  else return;
  float f = src[local];
  unsigned short hi = bf16_rne(f);
  float fh = __uint_as_float((unsigned)hi << 16);
  unsigned short lo = bf16_rne(f - fh);
  pool[base + local] = hi;
  pool[base + msize + local] = lo;
}

// ---------------- aggregation: out[v] = x[v] + inv_deg * sum x[src] ----------------
__global__ __launch_bounds__(256)
void agg_kernel(const float* __restrict__ x, const int* __restrict__ csr_src,
                const int* __restrict__ row_start, const int* __restrict__ deg,
                const float* __restrict__ inv_deg, float* __restrict__ out) {
  int node = blockIdx.x * 4 + (threadIdx.x >> 6);
  int lane = threadIdx.x & 63;
  if (node >= N_NODES) return;
  int beg = row_start[node];
  int end = beg + deg[node];
  float s0 = 0.f, s1 = 0.f, t0 = 0.f, t1 = 0.f;
  float u0 = 0.f, u1 = 0.f, v0 = 0.f, v1 = 0.f;
  int e = beg;
  for (; e + 3 < end; e += 4) {
    int i0 = csr_src[e], i1 = csr_src[e + 1], i2 = csr_src[e + 2], i3 = csr_src[e + 3];
    float2 a = *reinterpret_cast<const float2*>(x + (size_t)i0 * 128 + lane * 2);
    float2 b = *reinterpret_cast<const float2*>(x + (size_t)i1 * 128 + lane * 2);
    float2 c = *reinterpret_cast<const float2*>(x + (size_t)i2 * 128 + lane * 2);
    float2 d = *reinterpret_cast<const float2*>(x + (size_t)i3 * 128 + lane * 2);
    s0 += a.x; s1 += a.y; t0 += b.x; t1 += b.y;
    u0 += c.x; u1 += c.y; v0 += d.x; v1 += d.y;
  }
  for (; e < end; ++e) {
    int i0 = csr_src[e];
    float2 a = *reinterpret_cast<const float2*>(x + (size_t)i0 * 128 + lane * 2);
    s0 += a.x; s1 += a.y;
  }
  float inv = inv_deg[node];
  float2 xv = *reinterpret_cast<const float2*>(x + (size_t)node * 128 + lane * 2);
  float2 o = make_float2(xv.x + (s0 + t0 + u0 + v0) * inv,
                         xv.y + (s1 + t1 + u1 + v1) * inv);
  *reinterpret_cast<float2*>(out + (size_t)node * 128 + lane * 2) = o;
}

// ---------------- fused 2-GEMM MLP, split-bf16 MFMA ----------------
// Y = act2(relu(X @ Wa^T + ba) @ Wb^T + bb), X:[M][128], Wa:[128][128], Wb:[N2][128]
// NB2: n-subblocks per wave in GEMM2 (2 -> N2=128, 1 -> N2=64).
__device__ __forceinline__ int swz(int row, int b) {
  return (row * 256 + b) ^ ((row & 7) << 4);
}

template <int NB2, bool RELU2>
__global__ __launch_bounds__(256)
void fused_mlp(const float* __restrict__ X,
               const unsigned short* __restrict__ Wah, const unsigned short* __restrict__ Wal,
               const float* __restrict__ ba,
               const unsigned short* __restrict__ Wbh, const unsigned short* __restrict__ Wbl,
               const float* __restrict__ bb,
               float* __restrict__ Y, int M) {
  __shared__ unsigned short Ahi[64 * 128];  // 16 KB
  __shared__ unsigned short Alo[64 * 128];  // 16 KB
  const int tid = threadIdx.x;
  const int w = tid >> 6;
  const int l = tid & 63;
  const int lrow = l & 15;
  const int lg = l >> 4;
  const int m0 = blockIdx.x * 64;
  char* ahi = (char*)Ahi;
  char* alo = (char*)Alo;

  // --- B1 fragments into registers (wave w owns cols w*32 .. w*32+31)
  bf16x8 b1h[2][4], b1l[2][4];
  #pragma unroll
  for (int nb = 0; nb < 2; ++nb) {
    int col = w * 32 + nb * 16 + lrow;
    #pragma unroll
    for (int kk = 0; kk < 4; ++kk) {
      int idx = col * 128 + kk * 32 + lg * 8;
      b1h[nb][kk] = *reinterpret_cast<const bf16x8*>(Wah + idx);
      b1l[nb][kk] = *reinterpret_cast<const bf16x8*>(Wal + idx);
    }
  }

  // --- stage X tile as bf16 hi/lo (rows >= M -> 0)
  #pragma unroll
  for (int it = 0; it < 8; ++it) {
    int f = tid + it * 256;
    int row = f >> 5, c = f & 31;
    float4 v = make_float4(0.f, 0.f, 0.f, 0.f);
    if (m0 + row < M)
      v = *reinterpret_cast<const float4*>(X + (size_t)(m0 + row) * 128 + c * 4);
    ushort4 hi, lo;
    float fh;
    hi.x = bf16_rne(v.x); fh = __uint_as_float((unsigned)hi.x << 16); lo.x = bf16_rne(v.x - fh);
    hi.y = bf16_rne(v.y); fh = __uint_as_float((unsigned)hi.y << 16); lo.y = bf16_rne(v.y - fh);
    hi.z = bf16_rne(v.z); fh = __uint_as_float((unsigned)hi.z << 16); lo.z = bf16_rne(v.z - fh);
    hi.w = bf16_rne(v.w); fh = __uint_as_float((unsigned)hi.w << 16); lo.w = bf16_rne(v.w - fh);
    int bo = swz(row, c * 8);
    *reinterpret_cast<ushort4*>(ahi + bo) = hi;
    *reinterpret_cast<ushort4*>(alo + bo) = lo;
  }
  __syncthreads();

  // --- GEMM1: acc[i][nb] over m-sub i, n-sub nb
  f32x4 acc[4][2];
  #pragma unroll
  for (int i = 0; i < 4; ++i)
    #pragma unroll
    for (int nb = 0; nb < 2; ++nb)
      acc[i][nb] = (f32x4){0.f, 0.f, 0.f, 0.f};

  #pragma unroll
  for (int i = 0; i < 4; ++i) {
    #pragma unroll
    for (int kk = 0; kk < 4; ++kk) {
      int bo = swz(i * 16 + lrow, kk * 64 + lg * 16);
      bf16x8 ah = *reinterpret_cast<const bf16x8*>(ahi + bo);
      bf16x8 al = *reinterpret_cast<const bf16x8*>(alo + bo);
      #pragma unroll
      for (int nb = 0; nb < 2; ++nb) {
        acc[i][nb] = __builtin_amdgcn_mfma_f32_16x16x32_bf16(ah, b1h[nb][kk], acc[i][nb], 0, 0, 0);
        acc[i][nb] = __builtin_amdgcn_mfma_f32_16x16x32_bf16(al, b1h[nb][kk], acc[i][nb], 0, 0, 0);
        acc[i][nb] = __builtin_amdgcn_mfma_f32_16x16x32_bf16(ah, b1l[nb][kk], acc[i][nb], 0, 0, 0);
      }
    }
  }
  __syncthreads();  // all GEMM1 LDS reads done before h overwrite

  // --- B2 fragments
  bf16x8 b2h[NB2][4], b2l[NB2][4];
  const int cb2 = (NB2 == 2) ? w * 32 : w * 16;
  #pragma unroll
  for (int nb = 0; nb < NB2; ++nb) {
    int col = cb2 + nb * 16 + lrow;
    #pragma unroll
    for (int kk = 0; kk < 4; ++kk) {
      int idx = col * 128 + kk * 32 + lg * 8;
      b2h[nb][kk] = *reinterpret_cast<const bf16x8*>(Wbh + idx);
      b2l[nb][kk] = *reinterpret_cast<const bf16x8*>(Wbl + idx);
    }
  }

  // --- h = relu(acc + ba) -> LDS bf16 hi/lo
  #pragma unroll
  for (int i = 0; i < 4; ++i) {
    #pragma unroll
    for (int nb = 0; nb < 2; ++nb) {
      int col = w * 32 + nb * 16 + lrow;
      float bias = ba[col];
      #pragma unroll
      for (int r = 0; r < 4; ++r) {
        float v = fmaxf(acc[i][nb][r] + bias, 0.f);
        int row = i * 16 + lg * 4 + r;
        unsigned short h = bf16_rne(v);
        float fh = __uint_as_float((unsigned)h << 16);
        unsigned short lo2 = bf16_rne(v - fh);
        int bo = swz(row, col * 2);
        *reinterpret_cast<unsigned short*>(ahi + bo) = h;
        *reinterpret_cast<unsigned short*>(alo + bo) = lo2;
      }
    }
  }
  __syncthreads();

  // --- GEMM2
  f32x4 acc2[4][NB2];
  #pragma unroll
  for (int i = 0; i < 4; ++i)
    #pragma unroll
    for (int nb = 0; nb < NB2; ++nb)
      acc2[i][nb] = (f32x4){0.f, 0.f, 0.f, 0.f};

  #pragma unroll
  for (int i = 0; i < 4; ++i) {
    #pragma unroll
    for (int kk = 0; kk < 4; ++kk) {
      int bo = swz(i * 16 + lrow, kk * 64 + lg * 16);
      bf16x8 ah = *reinterpret_cast<const bf16x8*>(ahi + bo);
      bf16x8 al = *reinterpret_cast<const bf16x8*>(alo + bo);
      #pragma unroll
      for (int nb = 0; nb < NB2; ++nb) {
        acc2[i][nb] = __builtin_amdgcn_mfma_f32_16x16x32_bf16(ah, b2h[nb][kk], acc2[i][nb], 0, 0, 0);
        acc2[i][nb] = __builtin_amdgcn_mfma_f32_16x16x32_bf16(al, b2h[nb][kk], acc2[i][nb], 0, 0, 0);
        acc2[i][nb] = __builtin_amdgcn_mfma_f32_16x16x32_bf16(ah, b2l[nb][kk], acc2[i][nb], 0, 0, 0);
      }
    }
  }

  // --- epilogue
  constexpr int NOUT = NB2 * 64;
  #pragma unroll
  for (int i = 0; i < 4; ++i) {
    #pragma unroll
    for (int nb = 0; nb < NB2; ++nb) {
      int col = cb2 + nb * 16 + lrow;
      float bias = bb[col];
      #pragma unroll
      for (int r = 0; r < 4; ++r) {
        float v = acc2[i][nb][r] + bias;
        if (RELU2) v = fmaxf(v, 0.f);
        int row = m0 + i * 16 + lg * 4 + r;
        if (row < M) Y[(size_t)row * NOUT + col] = v;
      }
    }
  }
}

// ---------------- launch ----------------
extern "C" void kernel_launch(void* const* d_in, const int* in_sizes, int n_in,
                              void* d_out, int out_size, void* d_ws, size_t ws_size,
                              hipStream_t stream) {
  const float* feat = (const float*)d_in[0];
  const int*   esrc = (const int*)d_in[1];
  const int*   edst = (const int*)d_in[2];
  const float* W1a = (const float*)d_in[3];  const float* b1a = (const float*)d_in[4];
  const float* W1b = (const float*)d_in[5];  const float* b1b = (const float*)d_in[6];
  const float* W2a = (const float*)d_in[7];  const float* b2a = (const float*)d_in[8];
  const float* W2b = (const float*)d_in[9];  const float* b2b = (const float*)d_in[10];
  const float* W3a = (const float*)d_in[11]; const float* b3a = (const float*)d_in[12];
  const float* W3b = (const float*)d_in[13]; const float* b3b = (const float*)d_in[14];

  char* ws = (char*)d_ws;
  float* bufA      = (float*)(ws + OFF_BUFA);
  float* bufB      = (float*)(ws + OFF_BUFB);
  int*   row_start = (int*)  (ws + OFF_ROWSTART);
  int*   cnt       = (int*)  (ws + OFF_CNT);
  int*   cursor    = (int*)  (ws + OFF_CURSOR);
  int*   ctr       = (int*)  (ws + OFF_CTR);
  int*   csr       = (int*)  (ws + OFF_CSR);
  unsigned short* p = (unsigned short*)(ws + OFF_W);
  float* inv_deg   = (float*)(ws + OFF_INVDEG);

  // zero cnt + cursor + ctr in one shot (contiguous)
  hipMemsetAsync(ws + OFF_CNT, 0, 400016, stream);

  hist_kernel<<<(N_EDGES + 255) / 256, 256, 0, stream>>>(edst, cnt, N_EDGES);
  blockscan_kernel<<<(N_NODES + 255) / 256, 256, 0, stream>>>(cnt, row_start, inv_deg, ctr, N_NODES);
  scatter_kernel<<<(N_EDGES + 255) / 256, 256, 0, stream>>>(esrc, edst, row_start, cursor, csr, N_EDGES);
  wconvert<<<(90112 + 255) / 256, 256, 0, stream>>>(W1a, W1b, W2a, W2b, W3a, W3b, p);

  const int AB = (N_NODES + 3) / 4;      // 12500
  const int GB = (N_NODES + 63) / 64;    // 782

  // layer 1
  agg_kernel<<<AB, 256, 0, stream>>>(feat, csr, row_start, cnt, inv_deg, bufA);
  fused_mlp<2, true><<<GB, 256, 0, stream>>>(bufA, p + 0, p + 16384, b1a,
                                             p + 32768, p + 49152, b1b, bufB, N_NODES);
  // layer 2
  agg_kernel<<<AB, 256, 0, stream>>>(bufB, csr, row_start, cnt, inv_deg, bufA);
  fused_mlp<2, true><<<GB, 256, 0, stream>>>(bufA, p + 65536, p + 81920, b2a,
                                             p + 98304, p + 114688, b2b, bufB, N_NODES);
  // head
  fused_mlp<1, false><<<GB, 256, 0, stream>>>(bufB, p + 131072, p + 147456, b3a,
                                              p + 163840, p + 172032, b3b, (float*)d_out, N_NODES);
}

// Round 4
// 267.615 us; speedup vs baseline: 1.9276x; 1.1293x over previous
//
#include <hip/hip_runtime.h>

#define N_NODES 50000
#define N_EDGES 800000

typedef __attribute__((ext_vector_type(8))) short bf16x8;
typedef __attribute__((ext_vector_type(4))) float f32x4;

// ---------------- workspace layout (bytes) ----------------
#define OFF_BUFA      0UL
#define OFF_BUFB      25600000UL
#define OFF_CNT       51200000UL   // 200,000
#define OFF_CURSOR    51400000UL   // 200,000 (classic path only)
#define OFF_CTR       51600000UL   // 16
#define OFF_ROWSTART  51600016UL   // 200,004 (classic path only)
#define OFF_W         51800032UL   // 360,448 (bf16 hi/lo weight pool), 16B aligned
#define OFF_CSR       52160480UL   // classic: 3.2MB ; padded: 12.8MB
#define PAD_NEEDED    64960480UL   // end of padded CSR

__device__ __forceinline__ unsigned short bf16_rne(float f) {
  unsigned u = __float_as_uint(f);
  unsigned r = (u + 0x7FFFu + ((u >> 16) & 1u)) >> 16;
  return (unsigned short)r;
}

// ---------------- CSR build: padded single-pass ----------------
__global__ __launch_bounds__(256)
void scatter_pad(const int* __restrict__ src, const int* __restrict__ dst,
                 int* __restrict__ cnt, int* __restrict__ csr, int E) {
  int i = blockIdx.x * 256 + threadIdx.x;
  if (i < E) {
    int d = dst[i];
    int pos = atomicAdd(&cnt[d], 1);
    if (pos < 64) csr[(d << 6) + pos] = src[i];
  }
}

// ---------------- CSR build: classic 3-pass (fallback if ws too small) ----------------
__global__ __launch_bounds__(256)
void hist_kernel(const int* __restrict__ dst, int* __restrict__ cnt, int E) {
  int i = blockIdx.x * 256 + threadIdx.x;
  if (i < E) atomicAdd(&cnt[dst[i]], 1);
}

__global__ __launch_bounds__(256)
void blockscan_kernel(const int* __restrict__ cnt, int* __restrict__ row_start,
                      int* __restrict__ counter, int n) {
  __shared__ int wsum[4];
  __shared__ int sbase;
  int i = blockIdx.x * 256 + threadIdx.x;
  int lane = threadIdx.x & 63;
  int wid = threadIdx.x >> 6;
  int v = (i < n) ? cnt[i] : 0;
  int x = v;
  #pragma unroll
  for (int off = 1; off < 64; off <<= 1) {
    int y = __shfl_up(x, off);
    if (lane >= off) x += y;
  }
  if (lane == 63) wsum[wid] = x;
  __syncthreads();
  if (threadIdx.x == 0) {
    int t0 = wsum[0], t1 = wsum[1], t2 = wsum[2], t3 = wsum[3];
    sbase = atomicAdd(counter, t0 + t1 + t2 + t3);
    wsum[0] = 0; wsum[1] = t0; wsum[2] = t0 + t1; wsum[3] = t0 + t1 + t2;
  }
  __syncthreads();
  if (i < n) row_start[i] = sbase + wsum[wid] + (x - v);
}

__global__ __launch_bounds__(256)
void scatter_kernel(const int* __restrict__ src, const int* __restrict__ dst,
                    const int* __restrict__ row_start, int* __restrict__ cursor,
                    int* __restrict__ csr_src, int E) {
  int i = blockIdx.x * 256 + threadIdx.x;
  if (i < E) {
    int d = dst[i];
    int pos = atomicAdd(&cursor[d], 1);
    csr_src[row_start[d] + pos] = src[i];
  }
}

// ---------------- weights -> bf16 hi/lo, [n][k] row-major ----------------
__global__ __launch_bounds__(256)
void wconvert(const float* __restrict__ W1a, const float* __restrict__ W1b,
              const float* __restrict__ W2a, const float* __restrict__ W2b,
              const float* __restrict__ W3a, const float* __restrict__ W3b,
              unsigned short* __restrict__ pool) {
  int i = blockIdx.x * 256 + threadIdx.x;
  const float* src;
  int base, local, msize;
  if (i < 16384)      { src = W1a; base = 0;      local = i;          msize = 16384; }
  else if (i < 32768) { src = W1b; base = 32768;  local = i - 16384;  msize = 16384; }
  else if (i < 49152) { src = W2a; base = 65536;  local = i - 32768;  msize = 16384; }
  else if (i < 65536) { src = W2b; base = 98304;  local = i - 49152;  msize = 16384; }
  else if (i < 81920) { src = W3a; base = 131072; local = i - 65536;  msize = 16384; }
  else if (i < 90112) { src = W3b; base = 163840; local = i - 81920;  msize = 8192;  }
  else return;
  float f = src[local];
  unsigned short hi = bf16_rne(f);
  float fh = __uint_as_float((unsigned)hi << 16);
  unsigned short lo = bf16_rne(f - fh);
  pool[base + local] = hi;
  pool[base + msize + local] = lo;
}

// ---------------- aggregation: out[v] = x[v] + inv_deg * sum x[src] ----------------
// One wave per node. float4/lane, half-wave per edge-row -> 2 rows per gather,
// 8 gathers (16 edges) per iteration, fully masked (no serial tail).
template <bool PAD>
__global__ __launch_bounds__(256)
void agg_kernel(const float* __restrict__ x, const int* __restrict__ csr,
                const int* __restrict__ row_start, const int* __restrict__ cnt,
                float* __restrict__ out) {
  int node = blockIdx.x * 4 + (threadIdx.x >> 6);
  if (node >= N_NODES) return;
  const int lane = threadIdx.x & 63;
  const int half = lane >> 5;        // 0: even edge slot, 1: odd edge slot
  const int c4 = (lane & 31) * 4;    // feature column
  int degt = cnt[node];
  int dloop = PAD ? min(degt, 64) : degt;
  int beg = PAD ? (node << 6) : row_start[node];
  float inv = 1.0f / fmaxf((float)degt, 1.0f);

  f32x4 acc[8];
  #pragma unroll
  for (int j = 0; j < 8; ++j) acc[j] = (f32x4){0.f, 0.f, 0.f, 0.f};

  for (int t = 0; t < dloop; t += 16) {
    int idx[8];
    float m[8];
    #pragma unroll
    for (int j = 0; j < 8; ++j) {
      int ee = t + 2 * j + half;
      bool ok = ee < dloop;
      idx[j] = ok ? csr[beg + ee] : node;
      m[j] = ok ? 1.f : 0.f;
    }
    #pragma unroll
    for (int j = 0; j < 8; ++j) {
      f32x4 u = *reinterpret_cast<const f32x4*>(x + (size_t)idx[j] * 128 + c4);
      acc[j][0] = fmaf(m[j], u[0], acc[j][0]);
      acc[j][1] = fmaf(m[j], u[1], acc[j][1]);
      acc[j][2] = fmaf(m[j], u[2], acc[j][2]);
      acc[j][3] = fmaf(m[j], u[3], acc[j][3]);
    }
  }
  f32x4 s = acc[0];
  #pragma unroll
  for (int j = 1; j < 8; ++j) { s[0] += acc[j][0]; s[1] += acc[j][1]; s[2] += acc[j][2]; s[3] += acc[j][3]; }
  #pragma unroll
  for (int r = 0; r < 4; ++r) s[r] += __shfl_xor(s[r], 32);

  if (half == 0) {
    f32x4 xv = *reinterpret_cast<const f32x4*>(x + (size_t)node * 128 + c4);
    f32x4 o;
    #pragma unroll
    for (int r = 0; r < 4; ++r) o[r] = fmaf(s[r], inv, xv[r]);
    *reinterpret_cast<f32x4*>(out + (size_t)node * 128 + c4) = o;
  }
}

// ---------------- fused 2-GEMM MLP, split-bf16 MFMA ----------------
__device__ __forceinline__ int swz(int row, int b) {
  return (row * 256 + b) ^ ((row & 7) << 4);
}

template <int NB2, bool RELU2>
__global__ __launch_bounds__(256)
void fused_mlp(const float* __restrict__ X,
               const unsigned short* __restrict__ Wah, const unsigned short* __restrict__ Wal,
               const float* __restrict__ ba,
               const unsigned short* __restrict__ Wbh, const unsigned short* __restrict__ Wbl,
               const float* __restrict__ bb,
               float* __restrict__ Y, int M) {
  __shared__ unsigned short Ahi[64 * 128];  // 16 KB
  __shared__ unsigned short Alo[64 * 128];  // 16 KB
  const int tid = threadIdx.x;
  const int w = tid >> 6;
  const int l = tid & 63;
  const int lrow = l & 15;
  const int lg = l >> 4;
  const int m0 = blockIdx.x * 64;
  char* ahi = (char*)Ahi;
  char* alo = (char*)Alo;

  bf16x8 b1h[2][4], b1l[2][4];
  #pragma unroll
  for (int nb = 0; nb < 2; ++nb) {
    int col = w * 32 + nb * 16 + lrow;
    #pragma unroll
    for (int kk = 0; kk < 4; ++kk) {
      int idx = col * 128 + kk * 32 + lg * 8;
      b1h[nb][kk] = *reinterpret_cast<const bf16x8*>(Wah + idx);
      b1l[nb][kk] = *reinterpret_cast<const bf16x8*>(Wal + idx);
    }
  }

  #pragma unroll
  for (int it = 0; it < 8; ++it) {
    int f = tid + it * 256;
    int row = f >> 5, c = f & 31;
    float4 v = make_float4(0.f, 0.f, 0.f, 0.f);
    if (m0 + row < M)
      v = *reinterpret_cast<const float4*>(X + (size_t)(m0 + row) * 128 + c * 4);
    ushort4 hi, lo;
    float fh;
    hi.x = bf16_rne(v.x); fh = __uint_as_float((unsigned)hi.x << 16); lo.x = bf16_rne(v.x - fh);
    hi.y = bf16_rne(v.y); fh = __uint_as_float((unsigned)hi.y << 16); lo.y = bf16_rne(v.y - fh);
    hi.z = bf16_rne(v.z); fh = __uint_as_float((unsigned)hi.z << 16); lo.z = bf16_rne(v.z - fh);
    hi.w = bf16_rne(v.w); fh = __uint_as_float((unsigned)hi.w << 16); lo.w = bf16_rne(v.w - fh);
    int bo = swz(row, c * 8);
    *reinterpret_cast<ushort4*>(ahi + bo) = hi;
    *reinterpret_cast<ushort4*>(alo + bo) = lo;
  }
  __syncthreads();

  f32x4 acc[4][2];
  #pragma unroll
  for (int i = 0; i < 4; ++i)
    #pragma unroll
    for (int nb = 0; nb < 2; ++nb)
      acc[i][nb] = (f32x4){0.f, 0.f, 0.f, 0.f};

  #pragma unroll
  for (int i = 0; i < 4; ++i) {
    #pragma unroll
    for (int kk = 0; kk < 4; ++kk) {
      int bo = swz(i * 16 + lrow, kk * 64 + lg * 16);
      bf16x8 ah = *reinterpret_cast<const bf16x8*>(ahi + bo);
      bf16x8 al = *reinterpret_cast<const bf16x8*>(alo + bo);
      #pragma unroll
      for (int nb = 0; nb < 2; ++nb) {
        acc[i][nb] = __builtin_amdgcn_mfma_f32_16x16x32_bf16(ah, b1h[nb][kk], acc[i][nb], 0, 0, 0);
        acc[i][nb] = __builtin_amdgcn_mfma_f32_16x16x32_bf16(al, b1h[nb][kk], acc[i][nb], 0, 0, 0);
        acc[i][nb] = __builtin_amdgcn_mfma_f32_16x16x32_bf16(ah, b1l[nb][kk], acc[i][nb], 0, 0, 0);
      }
    }
  }
  __syncthreads();

  bf16x8 b2h[NB2][4], b2l[NB2][4];
  const int cb2 = (NB2 == 2) ? w * 32 : w * 16;
  #pragma unroll
  for (int nb = 0; nb < NB2; ++nb) {
    int col = cb2 + nb * 16 + lrow;
    #pragma unroll
    for (int kk = 0; kk < 4; ++kk) {
      int idx = col * 128 + kk * 32 + lg * 8;
      b2h[nb][kk] = *reinterpret_cast<const bf16x8*>(Wbh + idx);
      b2l[nb][kk] = *reinterpret_cast<const bf16x8*>(Wbl + idx);
    }
  }

  #pragma unroll
  for (int i = 0; i < 4; ++i) {
    #pragma unroll
    for (int nb = 0; nb < 2; ++nb) {
      int col = w * 32 + nb * 16 + lrow;
      float bias = ba[col];
      #pragma unroll
      for (int r = 0; r < 4; ++r) {
        float v = fmaxf(acc[i][nb][r] + bias, 0.f);
        int row = i * 16 + lg * 4 + r;
        unsigned short h = bf16_rne(v);
        float fh = __uint_as_float((unsigned)h << 16);
        unsigned short lo2 = bf16_rne(v - fh);
        int bo = swz(row, col * 2);
        *reinterpret_cast<unsigned short*>(ahi + bo) = h;
        *reinterpret_cast<unsigned short*>(alo + bo) = lo2;
      }
    }
  }
  __syncthreads();

  f32x4 acc2[4][NB2];
  #pragma unroll
  for (int i = 0; i < 4; ++i)
    #pragma unroll
    for (int nb = 0; nb < NB2; ++nb)
      acc2[i][nb] = (f32x4){0.f, 0.f, 0.f, 0.f};

  #pragma unroll
  for (int i = 0; i < 4; ++i) {
    #pragma unroll
    for (int kk = 0; kk < 4; ++kk) {
      int bo = swz(i * 16 + lrow, kk * 64 + lg * 16);
      bf16x8 ah = *reinterpret_cast<const bf16x8*>(ahi + bo);
      bf16x8 al = *reinterpret_cast<const bf16x8*>(alo + bo);
      #pragma unroll
      for (int nb = 0; nb < NB2; ++nb) {
        acc2[i][nb] = __builtin_amdgcn_mfma_f32_16x16x32_bf16(ah, b2h[nb][kk], acc2[i][nb], 0, 0, 0);
        acc2[i][nb] = __builtin_amdgcn_mfma_f32_16x16x32_bf16(al, b2h[nb][kk], acc2[i][nb], 0, 0, 0);
        acc2[i][nb] = __builtin_amdgcn_mfma_f32_16x16x32_bf16(ah, b2l[nb][kk], acc2[i][nb], 0, 0, 0);
      }
    }
  }

  constexpr int NOUT = NB2 * 64;
  #pragma unroll
  for (int i = 0; i < 4; ++i) {
    #pragma unroll
    for (int nb = 0; nb < NB2; ++nb) {
      int col = cb2 + nb * 16 + lrow;
      float bias = bb[col];
      #pragma unroll
      for (int r = 0; r < 4; ++r) {
        float v = acc2[i][nb][r] + bias;
        if (RELU2) v = fmaxf(v, 0.f);
        int row = m0 + i * 16 + lg * 4 + r;
        if (row < M) Y[(size_t)row * NOUT + col] = v;
      }
    }
  }
}

// ---------------- launch ----------------
extern "C" void kernel_launch(void* const* d_in, const int* in_sizes, int n_in,
                              void* d_out, int out_size, void* d_ws, size_t ws_size,
                              hipStream_t stream) {
  const float* feat = (const float*)d_in[0];
  const int*   esrc = (const int*)d_in[1];
  const int*   edst = (const int*)d_in[2];
  const float* W1a = (const float*)d_in[3];  const float* b1a = (const float*)d_in[4];
  const float* W1b = (const float*)d_in[5];  const float* b1b = (const float*)d_in[6];
  const float* W2a = (const float*)d_in[7];  const float* b2a = (const float*)d_in[8];
  const float* W2b = (const float*)d_in[9];  const float* b2b = (const float*)d_in[10];
  const float* W3a = (const float*)d_in[11]; const float* b3a = (const float*)d_in[12];
  const float* W3b = (const float*)d_in[13]; const float* b3b = (const float*)d_in[14];

  char* ws = (char*)d_ws;
  float* bufA      = (float*)(ws + OFF_BUFA);
  float* bufB      = (float*)(ws + OFF_BUFB);
  int*   cnt       = (int*)  (ws + OFF_CNT);
  int*   cursor    = (int*)  (ws + OFF_CURSOR);
  int*   ctr       = (int*)  (ws + OFF_CTR);
  int*   row_start = (int*)  (ws + OFF_ROWSTART);
  unsigned short* p = (unsigned short*)(ws + OFF_W);
  int*   csr       = (int*)  (ws + OFF_CSR);

  const bool padded = (ws_size >= PAD_NEEDED);

  // zero cnt + cursor + ctr in one shot (contiguous)
  hipMemsetAsync(ws + OFF_CNT, 0, 400016, stream);

  if (padded) {
    scatter_pad<<<(N_EDGES + 255) / 256, 256, 0, stream>>>(esrc, edst, cnt, csr, N_EDGES);
  } else {
    hist_kernel<<<(N_EDGES + 255) / 256, 256, 0, stream>>>(edst, cnt, N_EDGES);
    blockscan_kernel<<<(N_NODES + 255) / 256, 256, 0, stream>>>(cnt, row_start, ctr, N_NODES);
    scatter_kernel<<<(N_EDGES + 255) / 256, 256, 0, stream>>>(esrc, edst, row_start, cursor, csr, N_EDGES);
  }
  wconvert<<<(90112 + 255) / 256, 256, 0, stream>>>(W1a, W1b, W2a, W2b, W3a, W3b, p);

  const int AB = (N_NODES + 3) / 4;      // 12500
  const int GB = (N_NODES + 63) / 64;    // 782

  // layer 1
  if (padded) agg_kernel<true><<<AB, 256, 0, stream>>>(feat, csr, row_start, cnt, bufA);
  else        agg_kernel<false><<<AB, 256, 0, stream>>>(feat, csr, row_start, cnt, bufA);
  fused_mlp<2, true><<<GB, 256, 0, stream>>>(bufA, p + 0, p + 16384, b1a,
                                             p + 32768, p + 49152, b1b, bufB, N_NODES);
  // layer 2
  if (padded) agg_kernel<true><<<AB, 256, 0, stream>>>(bufB, csr, row_start, cnt, bufA);
  else        agg_kernel<false><<<AB, 256, 0, stream>>>(bufB, csr, row_start, cnt, bufA);
  fused_mlp<2, true><<<GB, 256, 0, stream>>>(bufA, p + 65536, p + 81920, b2a,
                                             p + 98304, p + 114688, b2b, bufB, N_NODES);
  // head
  fused_mlp<1, false><<<GB, 256, 0, stream>>>(bufB, p + 131072, p + 147456, b3a,
                                              p + 163840, p + 172032, b3b, (float*)d_out, N_NODES);
}